// Round 8
// baseline (699.256 us; speedup 1.0000x reference)
//
#include <hip/hip_runtime.h>

#define DFEAT 64

typedef __attribute__((ext_vector_type(8))) short bf16x8;   // 8 bf16 = 4 VGPRs
typedef __attribute__((ext_vector_type(4))) float f32x4;

// ---------------- bf16 helpers (OCP bfloat16, RNE pack) ----------------
__device__ __forceinline__ float bfhi(unsigned int u) {   // high 16 bits as bf16
    return __builtin_bit_cast(float, u & 0xFFFF0000u);
}
__device__ __forceinline__ float bflo(unsigned int u) {   // low 16 bits as bf16
    return __builtin_bit_cast(float, u << 16);
}
__device__ __forceinline__ unsigned short f2bf(float f) { // RNE
    unsigned int u = __builtin_bit_cast(unsigned int, f);
    u += 0x7FFFu + ((u >> 16) & 1u);
    return (unsigned short)(u >> 16);
}

// ============================================================================
// fp32 -> bf16 conversion of the input features (once per call)
// ============================================================================
__global__ void __launch_bounds__(256)
cvt_bf16_kernel(const float* __restrict__ in, unsigned short* __restrict__ outb,
                int n4) {   // n4 = total elements / 4
    int i = blockIdx.x * 256 + threadIdx.x;
    if (i >= n4) return;
    const float4 v = reinterpret_cast<const float4*>(in)[i];
    uint2 p;
    p.x = (unsigned int)f2bf(v.x) | ((unsigned int)f2bf(v.y) << 16);
    p.y = (unsigned int)f2bf(v.z) | ((unsigned int)f2bf(v.w) << 16);
    reinterpret_cast<uint2*>(outb)[i] = p;
}

// ============================================================================
// CSR build, binned two-pass.
// Bucket b = 256 consecutive dst nodes. NB = ceil(N/256) <= 512 (N=100000).
// Edges pack into u32: (dst & 255) << 24 | src   (needs src < 2^24).
// ============================================================================

__global__ void __launch_bounds__(256)
bucket_hist_kernel(const int* __restrict__ dsts, int* __restrict__ bhist, int E) {
    __shared__ int h[512];
    const int tid = threadIdx.x;
    h[tid] = 0; h[tid + 256] = 0;
    __syncthreads();
    for (int e = blockIdx.x * 256 + tid; e < E; e += gridDim.x * 256)
        atomicAdd(&h[dsts[e] >> 8], 1);
    __syncthreads();
    for (int b = tid; b < 512; b += 256)
        if (h[b]) atomicAdd(&bhist[b], h[b]);
}

__global__ void __launch_bounds__(256)
bucket_scan_kernel(const int* __restrict__ bhist, int* __restrict__ bbase,
                   int* __restrict__ bcur) {
    __shared__ int sm[512];
    const int tid = threadIdx.x;
    sm[tid] = bhist[tid]; sm[tid + 256] = bhist[tid + 256];
    __syncthreads();
    for (int s = 1; s < 512; s <<= 1) {
        int a0 = (tid >= s) ? sm[tid - s] : 0;
        int a1 = sm[tid + 256 - s];
        __syncthreads();
        sm[tid] += a0; sm[tid + 256] += a1;
        __syncthreads();
    }
    for (int b = tid; b < 512; b += 256) {
        int excl = b ? sm[b - 1] : 0;
        bbase[b] = excl; bcur[b] = excl;
    }
    if (tid == 0) bbase[512] = sm[511];
}

#define BIN_CH 2048
__global__ void __launch_bounds__(256)
bin_kernel(const int* __restrict__ srcs, const int* __restrict__ dsts,
           int* __restrict__ bcur, unsigned int* __restrict__ pairbuf, int E) {
    __shared__ int hist[512];
    __shared__ int sscan[512];
    __shared__ int gbase[512];
    __shared__ unsigned int staged[BIN_CH];
    __shared__ unsigned short sbkt[BIN_CH];

    const int tid = threadIdx.x;
    const int base = blockIdx.x * BIN_CH;
    const int chcnt = min(BIN_CH, E - base);

    hist[tid] = 0; hist[tid + 256] = 0;
    __syncthreads();

    unsigned int pk[8];
    unsigned short bb[8], rr[8];
#pragma unroll
    for (int k = 0; k < 8; ++k) {
        int i = k * 256 + tid;
        if (i < chcnt) {
            int e = base + i;
            int d = dsts[e];
            int s = srcs[e];
            int b = d >> 8;
            int r = atomicAdd(&hist[b], 1);
            pk[k] = ((unsigned int)(d & 255) << 24) | (unsigned int)s;
            bb[k] = (unsigned short)b;
            rr[k] = (unsigned short)r;
        } else {
            bb[k] = 0xFFFFu;
        }
    }
    __syncthreads();

    sscan[tid] = hist[tid]; sscan[tid + 256] = hist[tid + 256];
    __syncthreads();
    for (int s = 1; s < 512; s <<= 1) {
        int a0 = (tid >= s) ? sscan[tid - s] : 0;
        int a1 = sscan[tid + 256 - s];
        __syncthreads();
        sscan[tid] += a0; sscan[tid + 256] += a1;
        __syncthreads();
    }

    for (int b = tid; b < 512; b += 256) {
        int c = hist[b];
        gbase[b] = c ? atomicAdd(&bcur[b], c) : 0;
    }
    __syncthreads();

#pragma unroll
    for (int k = 0; k < 8; ++k) {
        if (bb[k] != 0xFFFFu) {
            int b = bb[k];
            int lpos = (b ? sscan[b - 1] : 0) + rr[k];
            staged[lpos] = pk[k];
            sbkt[lpos] = (unsigned short)b;
        }
    }
    __syncthreads();

    for (int i = tid; i < chcnt; i += 256) {
        int b = sbkt[i];
        int excl = b ? sscan[b - 1] : 0;
        pairbuf[gbase[b] + (i - excl)] = staged[i];
    }
}

__global__ void __launch_bounds__(256)
bucket_fill_kernel(const unsigned int* __restrict__ pairbuf,
                   const int* __restrict__ bbase,
                   int* __restrict__ rowptr, int* __restrict__ col,
                   int N, int E) {
    __shared__ int hist[256];
    __shared__ int scan_[256];
    __shared__ int cur[256];

    const int tid = threadIdx.x;
    const int b = blockIdx.x;
    const int node0 = b << 8;
    const int bb0 = bbase[b];
    const int cnt = bbase[b + 1] - bb0;

    hist[tid] = 0;
    __syncthreads();
    for (int i = tid; i < cnt; i += 256)
        atomicAdd(&hist[pairbuf[bb0 + i] >> 24], 1);
    __syncthreads();

    scan_[tid] = hist[tid];
    __syncthreads();
    for (int s = 1; s < 256; s <<= 1) {
        int a = (tid >= s) ? scan_[tid - s] : 0;
        __syncthreads();
        scan_[tid] += a;
        __syncthreads();
    }
    int excl = tid ? scan_[tid - 1] : 0;
    if (node0 + tid < N) rowptr[node0 + tid] = bb0 + excl;
    if (b == 0 && tid == 0) rowptr[N] = E;
    cur[tid] = bb0 + excl;
    __syncthreads();

    for (int i = tid; i < cnt; i += 256) {
        unsigned int p = pairbuf[bb0 + i];
        int pos = atomicAdd(&cur[p >> 24], 1);
        col[pos] = (int)(p & 0xFFFFFFu);
    }
}

// ============================================================================
// FUSED SAGE layer, 4 COOPERATIVE WAVES PER 16-NODE TILE (TLP fix).
//
// Rounds 5-7 showed the fused kernel is TLP-starved (6250 waves; ILP attempts
// cost occupancy and regressed). Now: block = 1 tile, 4 waves. Wave w
// accumulates neighbors j == w (mod 4) of its lane's node -- per-lane loop
// bound j<deg means NO mask-FMA (every iteration is a real neighbor; clamped
// prefetches are never accumulated). Partials combine via ds_add_f32 into
// accL[j][lane] ([j*64+lane] -> bank lane%32, 2-way = conflict-free).
// One barrier, then wave 0 forms the mean fragments and runs the verified
// MFMA + epilogue (unchanged from round 4/5).
//   lane = 16q + c: c -> node, q -> k-octet / feature quarter.
// 25K waves total, LDS 20.5KB -> 8 blocks/CU -> up to 32 waves/CU resident.
// ============================================================================
__global__ void __launch_bounds__(256, 4)
fused_sage_kernel(const unsigned short* __restrict__ xb,
                  const int* __restrict__ rowptr, const int* __restrict__ col,
                  const float* __restrict__ Wl, const float* __restrict__ bl,
                  const float* __restrict__ Wr,
                  unsigned short* __restrict__ h_out,
                  const int* __restrict__ batch, float* __restrict__ out,
                  int n_nodes, int final_layer) {
    __shared__ __align__(16) unsigned short Wlds[8192];   // 16 frags * 512 ushort
    __shared__ float accL[16 * 64];                       // [j][lane], 4KB

    const int tid = threadIdx.x;

    // ---- zero partial buffer + stage [Wl|Wr] -> bf16 A-frags in LDS ----
    for (int i = tid; i < 1024; i += 256) accL[i] = 0.f;
    for (int i4 = tid; i4 < 1024; i4 += 256) {
        const float4 wl = reinterpret_cast<const float4*>(Wl)[i4];
        const float4 wr = reinterpret_cast<const float4*>(Wr)[i4];
        const int feat = i4 >> 4;
        const int n = feat >> 4, cc = feat & 15;
        const int k0 = (i4 & 15) << 2;           // 4 consecutive k, same octet half
        const int qq = (k0 >> 3) & 3, tl = k0 >> 5, j0 = k0 & 7;
        const int lofs = (qq * 16 + cc) * 8 + j0;
        uint2 pl, pr;
        pl.x = (unsigned int)f2bf(wl.x) | ((unsigned int)f2bf(wl.y) << 16);
        pl.y = (unsigned int)f2bf(wl.z) | ((unsigned int)f2bf(wl.w) << 16);
        pr.x = (unsigned int)f2bf(wr.x) | ((unsigned int)f2bf(wr.y) << 16);
        pr.y = (unsigned int)f2bf(wr.z) | ((unsigned int)f2bf(wr.w) << 16);
        *reinterpret_cast<uint2*>(&Wlds[(n * 4 + tl) * 512 + lofs]) = pl;
        *reinterpret_cast<uint2*>(&Wlds[(n * 4 + 2 + tl) * 512 + lofs]) = pr;
    }
    __syncthreads();

    const int w = tid >> 6;          // wave id = neighbor-residue class
    const int lane = tid & 63;
    const int c = lane & 15;         // node within tile
    const int q = lane >> 4;         // k-octet / feature quarter

    const int base = blockIdx.x << 4;          // grid == #tiles exactly
    const bool valid = (base + c) < n_nodes;
    const int node = valid ? (base + c) : (n_nodes - 1);

    const uint4* rows4 = reinterpret_cast<const uint4*>(xb);   // 8 uint4 per row
    const int st = rowptr[node];
    const int deg = valid ? (rowptr[node + 1] - st) : 0;

    // ---- gather quarter w: j = w, w+4, w+8, ... (no masks needed) ----
    float accA[8], accB[8];
#pragma unroll
    for (int j = 0; j < 8; ++j) { accA[j] = 0.f; accB[j] = 0.f; }

    if (deg > w) {
        const int dm1 = deg - 1;
        const int* cp = col + st;
        // depth-2 pipeline: row(j) in flight, col(j+4) in flight
        int c0 = cp[w];
        uint4 a0 = rows4[(size_t)c0 * 8 + q];
        uint4 b0 = rows4[(size_t)c0 * 8 + 4 + q];
        int c1 = cp[min(w + 4, dm1)];
        for (int j = w; j < deg; j += 4) {
            const int c2 = cp[min(j + 8, dm1)];          // col prefetch j+8
            const uint4 a1 = rows4[(size_t)c1 * 8 + q];  // row j+4 (dup at tail)
            const uint4 b1 = rows4[(size_t)c1 * 8 + 4 + q];
            accA[0] += bflo(a0.x); accA[1] += bfhi(a0.x);
            accA[2] += bflo(a0.y); accA[3] += bfhi(a0.y);
            accA[4] += bflo(a0.z); accA[5] += bfhi(a0.z);
            accA[6] += bflo(a0.w); accA[7] += bfhi(a0.w);
            accB[0] += bflo(b0.x); accB[1] += bfhi(b0.x);
            accB[2] += bflo(b0.y); accB[3] += bfhi(b0.y);
            accB[4] += bflo(b0.z); accB[5] += bfhi(b0.z);
            accB[6] += bflo(b0.w); accB[7] += bfhi(b0.w);
            a0 = a1; b0 = b1; c1 = c2;
        }
        // deposit partials (bank-friendly: addr = j*64+lane -> bank lane%32)
#pragma unroll
        for (int j = 0; j < 8; ++j) {
            atomicAdd(&accL[j * 64 + lane], accA[j]);
            atomicAdd(&accL[(8 + j) * 64 + lane], accB[j]);
        }
    }
    __syncthreads();

    if (w != 0) return;              // waves 1-3 done (both barriers passed)

    // ---- wave 0: mean fragments from combined partials ----
    const float inv = (deg > 0) ? (1.0f / (float)deg) : 0.0f;
    bf16x8 F0, F1;
#pragma unroll
    for (int j = 0; j < 8; ++j) {
        F0[j] = (short)f2bf(accL[j * 64 + lane] * inv);
        F1[j] = (short)f2bf(accL[(8 + j) * 64 + lane] * inv);
    }
    // x (root) fragments
    const uint4* xrow = reinterpret_cast<const uint4*>(&xb[(size_t)node * 64]);
    const bf16x8 F2 = __builtin_bit_cast(bf16x8, xrow[q]);        // k 64..95
    const bf16x8 F3 = __builtin_bit_cast(bf16x8, xrow[4 + q]);    // k 96..127

    // ---- MFMA: D = [Wl|Wr] @ [mean|x]^T ----
    const bf16x8* fragp = reinterpret_cast<const bf16x8*>(Wlds);  // [f*64 + lane]
    f32x4 acc[4];
#pragma unroll
    for (int n = 0; n < 4; ++n) acc[n] = (f32x4){0.f, 0.f, 0.f, 0.f};

#pragma unroll
    for (int n = 0; n < 4; ++n) {
        bf16x8 w0 = fragp[(n * 4 + 0) * 64 + lane];   // Wl, k 0..31
        bf16x8 w1 = fragp[(n * 4 + 1) * 64 + lane];   // Wl, k 32..63
        bf16x8 w2 = fragp[(n * 4 + 2) * 64 + lane];   // Wr, k 0..31
        bf16x8 w3 = fragp[(n * 4 + 3) * 64 + lane];   // Wr, k 32..63
        acc[n] = __builtin_amdgcn_mfma_f32_16x16x32_bf16(w0, F0, acc[n], 0, 0, 0);
        acc[n] = __builtin_amdgcn_mfma_f32_16x16x32_bf16(w1, F1, acc[n], 0, 0, 0);
        acc[n] = __builtin_amdgcn_mfma_f32_16x16x32_bf16(w2, F2, acc[n], 0, 0, 0);
        acc[n] = __builtin_amdgcn_mfma_f32_16x16x32_bf16(w3, F3, acc[n], 0, 0, 0);
    }

    // ---- epilogue: bias, L2 norm over features (this lane's node), relu ----
    float v[4][4];
    float ss = 0.f;
#pragma unroll
    for (int n = 0; n < 4; ++n) {
        const float4 b4 = reinterpret_cast<const float4*>(bl)[n * 4 + q]; // feats 16n+4q+..
        v[n][0] = acc[n][0] + b4.x;
        v[n][1] = acc[n][1] + b4.y;
        v[n][2] = acc[n][2] + b4.z;
        v[n][3] = acc[n][3] + b4.w;
#pragma unroll
        for (int r = 0; r < 4; ++r) ss += v[n][r] * v[n][r];
    }
    ss += __shfl_xor(ss, 16, 64);
    ss += __shfl_xor(ss, 32, 64);
    const float nrm = 1.0f / fmaxf(sqrtf(ss), 1e-12f);

    if (!final_layer) {
        if (valid) {
            uint2* dst = reinterpret_cast<uint2*>(&h_out[(size_t)(base + c) * 64]);
#pragma unroll
            for (int n = 0; n < 4; ++n) {
                float o0 = fmaxf(v[n][0] * nrm, 0.f), o1 = fmaxf(v[n][1] * nrm, 0.f);
                float o2 = fmaxf(v[n][2] * nrm, 0.f), o3 = fmaxf(v[n][3] * nrm, 0.f);
                uint2 p;
                p.x = (unsigned int)f2bf(o0) | ((unsigned int)f2bf(o1) << 16);
                p.y = (unsigned int)f2bf(o2) | ((unsigned int)f2bf(o3) << 16);
                dst[n * 4 + q] = p;       // ushorts (base+c)*64 + 16n + 4q ..
            }
        }
    } else {
        float o[4][4];
#pragma unroll
        for (int n = 0; n < 4; ++n)
#pragma unroll
            for (int r = 0; r < 4; ++r)
                o[n][r] = valid ? fmaxf(v[n][r] * nrm, 0.f) : 0.f;

        const int lastn = min(base + 15, n_nodes - 1);
        const int gb0 = batch[base];
        if (gb0 == batch[lastn]) {
            // graph-uniform tile: reduce over the 16 nodes, 1 atomic per feat
#pragma unroll
            for (int n = 0; n < 4; ++n)
#pragma unroll
                for (int r = 0; r < 4; ++r) {
                    float s = o[n][r];
                    s += __shfl_xor(s, 1, 64);
                    s += __shfl_xor(s, 2, 64);
                    s += __shfl_xor(s, 4, 64);
                    s += __shfl_xor(s, 8, 64);
                    if (c == 0)
                        atomicAdd(&out[(size_t)gb0 * DFEAT + n * 16 + q * 4 + r], s);
                }
        } else {
            if (valid) {
                const int gb = batch[base + c];
#pragma unroll
                for (int n = 0; n < 4; ++n)
#pragma unroll
                    for (int r = 0; r < 4; ++r)
                        atomicAdd(&out[(size_t)gb * DFEAT + n * 16 + q * 4 + r], o[n][r]);
            }
        }
    }
}

// ============================================================================
extern "C" void kernel_launch(void* const* d_in, const int* in_sizes, int n_in,
                              void* d_out, int out_size, void* d_ws, size_t ws_size,
                              hipStream_t stream) {
    const float* x_raw = (const float*)d_in[0];
    const int*   eidx  = (const int*)d_in[1];
    const int*   batch = (const int*)d_in[2];
    const float* Wl0 = (const float*)d_in[3];
    const float* bl0 = (const float*)d_in[4];
    const float* Wr0 = (const float*)d_in[5];
    const float* Wl1 = (const float*)d_in[6];
    const float* bl1 = (const float*)d_in[7];
    const float* Wr1 = (const float*)d_in[8];
    const float* Wl2 = (const float*)d_in[9];
    const float* bl2 = (const float*)d_in[10];
    const float* Wr2 = (const float*)d_in[11];

    const int N = in_sizes[0] / DFEAT;
    const int E = in_sizes[1] / 2;
    const int* srcs = eidx;
    const int* dsts = eidx + E;
    float* out = (float*)d_out;

    const int NB = (N + 255) >> 8;   // buckets of 256 nodes; N=100000 -> 391 (<=512)

    char* ws = (char*)d_ws;
    auto align512 = [](size_t v) { return (v + 511) & ~(size_t)511; };
    size_t off = 0;
    int* rowptr = (int*)(ws + off); off += align512(((size_t)N + 1) * 4);
    int* col    = (int*)(ws + off); off += align512((size_t)E * 4);
    int* bhist  = (int*)(ws + off); off += align512(512 * 4);
    int* bbase  = (int*)(ws + off); off += align512(513 * 4);
    int* bcur   = (int*)(ws + off); off += align512(512 * 4);
    unsigned short* xb = (unsigned short*)(ws + off); off += align512((size_t)N * DFEAT * 2);
    unsigned short* hA = (unsigned short*)(ws + off); off += align512((size_t)N * DFEAT * 2);
    unsigned short* hB = (unsigned short*)(ws + off);
    // pairbuf only lives during CSR build, which completes before hA is first
    // written (layer-0 fused kernel) -> alias it onto hA. E*4 (6.4MB) <= N*128B.
    unsigned int* pairbuf = (unsigned int*)hA;

    hipMemsetAsync(bhist, 0, 512 * 4, stream);
    hipMemsetAsync(out, 0, (size_t)out_size * 4, stream);

    // input fp32 -> bf16 (once)
    const int n4 = N * DFEAT / 4;
    cvt_bf16_kernel<<<(n4 + 255) / 256, 256, 0, stream>>>(x_raw, xb, n4);

    // CSR build, binned two-pass (once)
    bucket_hist_kernel<<<512, 256, 0, stream>>>(dsts, bhist, E);
    bucket_scan_kernel<<<1, 256, 0, stream>>>(bhist, bbase, bcur);
    bin_kernel<<<(E + BIN_CH - 1) / BIN_CH, 256, 0, stream>>>(srcs, dsts, bcur, pairbuf, E);
    bucket_fill_kernel<<<NB, 256, 0, stream>>>(pairbuf, bbase, rowptr, col, N, E);

    // fused layers: 1 tile per BLOCK, 4 cooperative waves
    const int tiles = (N + 15) / 16;

    fused_sage_kernel<<<tiles, 256, 0, stream>>>(xb, rowptr, col, Wl0, bl0, Wr0,
                                                 hA, nullptr, nullptr, N, 0);
    fused_sage_kernel<<<tiles, 256, 0, stream>>>(hA, rowptr, col, Wl1, bl1, Wr1,
                                                 hB, nullptr, nullptr, N, 0);
    fused_sage_kernel<<<tiles, 256, 0, stream>>>(hB, rowptr, col, Wl2, bl2, Wr2,
                                                 nullptr, batch, out, N, 1);
}

// Round 9
// 360.697 us; speedup vs baseline: 1.9386x; 1.9386x over previous
//
#include <hip/hip_runtime.h>

#define DFEAT 64

typedef __attribute__((ext_vector_type(8))) short bf16x8;   // 8 bf16 = 4 VGPRs
typedef __attribute__((ext_vector_type(4))) float f32x4;

// ---------------- bf16 helpers (OCP bfloat16, RNE pack) ----------------
__device__ __forceinline__ float bfhi(unsigned int u) {   // high 16 bits as bf16
    return __builtin_bit_cast(float, u & 0xFFFF0000u);
}
__device__ __forceinline__ float bflo(unsigned int u) {   // low 16 bits as bf16
    return __builtin_bit_cast(float, u << 16);
}
__device__ __forceinline__ unsigned short f2bf(float f) { // RNE
    unsigned int u = __builtin_bit_cast(unsigned int, f);
    u += 0x7FFFu + ((u >> 16) & 1u);
    return (unsigned short)(u >> 16);
}

// ============================================================================
// fp32 -> bf16 conversion of the input features (once per call)
// ============================================================================
__global__ void __launch_bounds__(256)
cvt_bf16_kernel(const float* __restrict__ in, unsigned short* __restrict__ outb,
                int n4) {   // n4 = total elements / 4
    int i = blockIdx.x * 256 + threadIdx.x;
    if (i >= n4) return;
    const float4 v = reinterpret_cast<const float4*>(in)[i];
    uint2 p;
    p.x = (unsigned int)f2bf(v.x) | ((unsigned int)f2bf(v.y) << 16);
    p.y = (unsigned int)f2bf(v.z) | ((unsigned int)f2bf(v.w) << 16);
    reinterpret_cast<uint2*>(outb)[i] = p;
}

// ============================================================================
// Weight fragment pre-conversion (once per layer): [Wl|Wr] fp32 -> bf16 MFMA
// A-fragments in GLOBAL memory (16 frags * 64 lanes * 8 bf16 = 16KB, L2-hot).
// element (feat,k) of Wsrc -> frag f=(feat>>4)*4 + isWr*2 + (k>>5),
// lane = ((k>>3)&3)*16 + (feat&15), elem j = k&7.  (verified mapping, r4-r7)
// ============================================================================
__global__ void __launch_bounds__(256)
wfrag_cvt_kernel(const float* __restrict__ Wl, const float* __restrict__ Wr,
                 unsigned short* __restrict__ wfrag) {
    const int i4 = blockIdx.x * 256 + threadIdx.x;
    if (i4 >= 1024) return;
    const float4 wl = reinterpret_cast<const float4*>(Wl)[i4];
    const float4 wr = reinterpret_cast<const float4*>(Wr)[i4];
    const int feat = i4 >> 4;
    const int n = feat >> 4, cc = feat & 15;
    const int k0 = (i4 & 15) << 2;           // 4 consecutive k, same octet half
    const int qq = (k0 >> 3) & 3, tl = k0 >> 5, j0 = k0 & 7;
    const int lofs = (qq * 16 + cc) * 8 + j0;
    uint2 pl, pr;
    pl.x = (unsigned int)f2bf(wl.x) | ((unsigned int)f2bf(wl.y) << 16);
    pl.y = (unsigned int)f2bf(wl.z) | ((unsigned int)f2bf(wl.w) << 16);
    pr.x = (unsigned int)f2bf(wr.x) | ((unsigned int)f2bf(wr.y) << 16);
    pr.y = (unsigned int)f2bf(wr.z) | ((unsigned int)f2bf(wr.w) << 16);
    *reinterpret_cast<uint2*>(&wfrag[(n * 4 + tl) * 512 + lofs]) = pl;
    *reinterpret_cast<uint2*>(&wfrag[(n * 4 + 2 + tl) * 512 + lofs]) = pr;
}

// ============================================================================
// CSR build, binned two-pass.
// ============================================================================

__global__ void __launch_bounds__(256)
bucket_hist_kernel(const int* __restrict__ dsts, int* __restrict__ bhist, int E) {
    __shared__ int h[512];
    const int tid = threadIdx.x;
    h[tid] = 0; h[tid + 256] = 0;
    __syncthreads();
    for (int e = blockIdx.x * 256 + tid; e < E; e += gridDim.x * 256)
        atomicAdd(&h[dsts[e] >> 8], 1);
    __syncthreads();
    for (int b = tid; b < 512; b += 256)
        if (h[b]) atomicAdd(&bhist[b], h[b]);
}

__global__ void __launch_bounds__(256)
bucket_scan_kernel(const int* __restrict__ bhist, int* __restrict__ bbase,
                   int* __restrict__ bcur) {
    __shared__ int sm[512];
    const int tid = threadIdx.x;
    sm[tid] = bhist[tid]; sm[tid + 256] = bhist[tid + 256];
    __syncthreads();
    for (int s = 1; s < 512; s <<= 1) {
        int a0 = (tid >= s) ? sm[tid - s] : 0;
        int a1 = sm[tid + 256 - s];
        __syncthreads();
        sm[tid] += a0; sm[tid + 256] += a1;
        __syncthreads();
    }
    for (int b = tid; b < 512; b += 256) {
        int excl = b ? sm[b - 1] : 0;
        bbase[b] = excl; bcur[b] = excl;
    }
    if (tid == 0) bbase[512] = sm[511];
}

#define BIN_CH 2048
__global__ void __launch_bounds__(256)
bin_kernel(const int* __restrict__ srcs, const int* __restrict__ dsts,
           int* __restrict__ bcur, unsigned int* __restrict__ pairbuf, int E) {
    __shared__ int hist[512];
    __shared__ int sscan[512];
    __shared__ int gbase[512];
    __shared__ unsigned int staged[BIN_CH];
    __shared__ unsigned short sbkt[BIN_CH];

    const int tid = threadIdx.x;
    const int base = blockIdx.x * BIN_CH;
    const int chcnt = min(BIN_CH, E - base);

    hist[tid] = 0; hist[tid + 256] = 0;
    __syncthreads();

    unsigned int pk[8];
    unsigned short bb[8], rr[8];
#pragma unroll
    for (int k = 0; k < 8; ++k) {
        int i = k * 256 + tid;
        if (i < chcnt) {
            int e = base + i;
            int d = dsts[e];
            int s = srcs[e];
            int b = d >> 8;
            int r = atomicAdd(&hist[b], 1);
            pk[k] = ((unsigned int)(d & 255) << 24) | (unsigned int)s;
            bb[k] = (unsigned short)b;
            rr[k] = (unsigned short)r;
        } else {
            bb[k] = 0xFFFFu;
        }
    }
    __syncthreads();

    sscan[tid] = hist[tid]; sscan[tid + 256] = hist[tid + 256];
    __syncthreads();
    for (int s = 1; s < 512; s <<= 1) {
        int a0 = (tid >= s) ? sscan[tid - s] : 0;
        int a1 = sscan[tid + 256 - s];
        __syncthreads();
        sscan[tid] += a0; sscan[tid + 256] += a1;
        __syncthreads();
    }

    for (int b = tid; b < 512; b += 256) {
        int c = hist[b];
        gbase[b] = c ? atomicAdd(&bcur[b], c) : 0;
    }
    __syncthreads();

#pragma unroll
    for (int k = 0; k < 8; ++k) {
        if (bb[k] != 0xFFFFu) {
            int b = bb[k];
            int lpos = (b ? sscan[b - 1] : 0) + rr[k];
            staged[lpos] = pk[k];
            sbkt[lpos] = (unsigned short)b;
        }
    }
    __syncthreads();

    for (int i = tid; i < chcnt; i += 256) {
        int b = sbkt[i];
        int excl = b ? sscan[b - 1] : 0;
        pairbuf[gbase[b] + (i - excl)] = staged[i];
    }
}

__global__ void __launch_bounds__(256)
bucket_fill_kernel(const unsigned int* __restrict__ pairbuf,
                   const int* __restrict__ bbase,
                   int* __restrict__ rowptr, int* __restrict__ col,
                   int N, int E) {
    __shared__ int hist[256];
    __shared__ int scan_[256];
    __shared__ int cur[256];

    const int tid = threadIdx.x;
    const int b = blockIdx.x;
    const int node0 = b << 8;
    const int bb0 = bbase[b];
    const int cnt = bbase[b + 1] - bb0;

    hist[tid] = 0;
    __syncthreads();
    for (int i = tid; i < cnt; i += 256)
        atomicAdd(&hist[pairbuf[bb0 + i] >> 24], 1);
    __syncthreads();

    scan_[tid] = hist[tid];
    __syncthreads();
    for (int s = 1; s < 256; s <<= 1) {
        int a = (tid >= s) ? scan_[tid - s] : 0;
        __syncthreads();
        scan_[tid] += a;
        __syncthreads();
    }
    int excl = tid ? scan_[tid - 1] : 0;
    if (node0 + tid < N) rowptr[node0 + tid] = bb0 + excl;
    if (b == 0 && tid == 0) rowptr[N] = E;
    cur[tid] = bb0 + excl;
    __syncthreads();

    for (int i = tid; i < cnt; i += 256) {
        unsigned int p = pairbuf[bb0 + i];
        int pos = atomicAdd(&cur[p >> 24], 1);
        col[pos] = (int)(p & 0xFFFFFFu);
    }
}

// ============================================================================
// FUSED SAGE layer, 4 cooperative waves per 16-node tile (round-8 REPAIRED):
//  - weights come pre-fragmented from GLOBAL (wfrag, L2-hot) -> LDS holds
//    ONLY the 16KB partial buffer -> 9 blocks/CU by LDS.
//  - __launch_bounds__(256,8): VGPR cap 64 -> up to 8 waves/SIMD = 32/CU.
//  - partial deposit: 4x ds_write_b128 per lane into part[(w*4+s)*64+lane]
//    (consecutive lanes 16B apart: conflict-free; NO atomics, NO zero-init
//    since every wave writes its full slice unconditionally).
// Wave w accumulates neighbors j == w (mod 4) of its lane's node (no mask
// FMAs; clamped prefetches are never accumulated). One barrier; wave 0
// combines 16 ds_read_b128 + vector adds, forms fragments, runs the
// verified MFMA + epilogue.  lane = 16q + c: c -> node, q -> k-octet.
// ============================================================================
__global__ void __launch_bounds__(256, 8)
fused_sage_kernel(const unsigned short* __restrict__ xb,
                  const int* __restrict__ rowptr, const int* __restrict__ col,
                  const unsigned short* __restrict__ wfrag,
                  const float* __restrict__ bl,
                  unsigned short* __restrict__ h_out,
                  const int* __restrict__ batch, float* __restrict__ out,
                  int n_nodes, int final_layer) {
    __shared__ f32x4 part[1024];     // [(w*4+s)][lane] : 16 KB

    const int tid = threadIdx.x;
    const int w = tid >> 6;          // wave id = neighbor-residue class
    const int lane = tid & 63;
    const int c = lane & 15;         // node within tile
    const int q = lane >> 4;         // k-octet / feature quarter

    const int base = blockIdx.x << 4;
    const bool valid = (base + c) < n_nodes;
    const int node = valid ? (base + c) : (n_nodes - 1);

    const uint4* rows4 = reinterpret_cast<const uint4*>(xb);   // 8 uint4 per row
    const int st = rowptr[node];
    const int deg = valid ? (rowptr[node + 1] - st) : 0;

    // ---- gather quarter w: j = w, w+4, w+8, ... (depth-2 pipeline) ----
    float accA[8], accB[8];
#pragma unroll
    for (int j = 0; j < 8; ++j) { accA[j] = 0.f; accB[j] = 0.f; }

    if (deg > w) {
        const int dm1 = deg - 1;
        const int* cp = col + st;
        int c0 = cp[w];
        uint4 a0 = rows4[(size_t)c0 * 8 + q];
        uint4 b0 = rows4[(size_t)c0 * 8 + 4 + q];
        int c1 = cp[min(w + 4, dm1)];
        for (int j = w; j < deg; j += 4) {
            const int c2 = cp[min(j + 8, dm1)];          // col prefetch j+8
            const uint4 a1 = rows4[(size_t)c1 * 8 + q];  // row j+4 (dup at tail)
            const uint4 b1 = rows4[(size_t)c1 * 8 + 4 + q];
            accA[0] += bflo(a0.x); accA[1] += bfhi(a0.x);
            accA[2] += bflo(a0.y); accA[3] += bfhi(a0.y);
            accA[4] += bflo(a0.z); accA[5] += bfhi(a0.z);
            accA[6] += bflo(a0.w); accA[7] += bfhi(a0.w);
            accB[0] += bflo(b0.x); accB[1] += bfhi(b0.x);
            accB[2] += bflo(b0.y); accB[3] += bfhi(b0.y);
            accB[4] += bflo(b0.z); accB[5] += bfhi(b0.z);
            accB[6] += bflo(b0.w); accB[7] += bfhi(b0.w);
            a0 = a1; b0 = b1; c1 = c2;
        }
    }
    // deposit partial slice (vector stores, no conflicts, no atomics)
    part[(w * 4 + 0) * 64 + lane] = (f32x4){accA[0], accA[1], accA[2], accA[3]};
    part[(w * 4 + 1) * 64 + lane] = (f32x4){accA[4], accA[5], accA[6], accA[7]};
    part[(w * 4 + 2) * 64 + lane] = (f32x4){accB[0], accB[1], accB[2], accB[3]};
    part[(w * 4 + 3) * 64 + lane] = (f32x4){accB[4], accB[5], accB[6], accB[7]};
    __syncthreads();

    if (w != 0) return;              // waves 1-3 done

    // ---- wave 0: combine partials -> mean fragments ----
    f32x4 sA0 = part[0 * 64 + lane]; f32x4 sA1 = part[1 * 64 + lane];
    f32x4 sB0 = part[2 * 64 + lane]; f32x4 sB1 = part[3 * 64 + lane];
#pragma unroll
    for (int ww = 1; ww < 4; ++ww) {
        sA0 += part[(ww * 4 + 0) * 64 + lane];
        sA1 += part[(ww * 4 + 1) * 64 + lane];
        sB0 += part[(ww * 4 + 2) * 64 + lane];
        sB1 += part[(ww * 4 + 3) * 64 + lane];
    }

    const float inv = (deg > 0) ? (1.0f / (float)deg) : 0.0f;
    bf16x8 F0, F1;
#pragma unroll
    for (int j = 0; j < 4; ++j) {
        F0[j]     = (short)f2bf(sA0[j] * inv);
        F0[4 + j] = (short)f2bf(sA1[j] * inv);
        F1[j]     = (short)f2bf(sB0[j] * inv);
        F1[4 + j] = (short)f2bf(sB1[j] * inv);
    }
    // x (root) fragments
    const uint4* xrow = reinterpret_cast<const uint4*>(&xb[(size_t)node * 64]);
    const bf16x8 F2 = __builtin_bit_cast(bf16x8, xrow[q]);        // k 64..95
    const bf16x8 F3 = __builtin_bit_cast(bf16x8, xrow[4 + q]);    // k 96..127

    // ---- MFMA: D = [Wl|Wr] @ [mean|x]^T (A-frags from global wfrag) ----
    const bf16x8* fragp = reinterpret_cast<const bf16x8*>(wfrag); // [f*64 + lane]
    f32x4 acc[4];
#pragma unroll
    for (int n = 0; n < 4; ++n) acc[n] = (f32x4){0.f, 0.f, 0.f, 0.f};

#pragma unroll
    for (int n = 0; n < 4; ++n) {
        bf16x8 w0 = fragp[(n * 4 + 0) * 64 + lane];   // Wl, k 0..31
        bf16x8 w1 = fragp[(n * 4 + 1) * 64 + lane];   // Wl, k 32..63
        bf16x8 w2 = fragp[(n * 4 + 2) * 64 + lane];   // Wr, k 0..31
        bf16x8 w3 = fragp[(n * 4 + 3) * 64 + lane];   // Wr, k 32..63
        acc[n] = __builtin_amdgcn_mfma_f32_16x16x32_bf16(w0, F0, acc[n], 0, 0, 0);
        acc[n] = __builtin_amdgcn_mfma_f32_16x16x32_bf16(w1, F1, acc[n], 0, 0, 0);
        acc[n] = __builtin_amdgcn_mfma_f32_16x16x32_bf16(w2, F2, acc[n], 0, 0, 0);
        acc[n] = __builtin_amdgcn_mfma_f32_16x16x32_bf16(w3, F3, acc[n], 0, 0, 0);
    }

    // ---- epilogue: bias, L2 norm over features (this lane's node), relu ----
    float v[4][4];
    float ss = 0.f;
#pragma unroll
    for (int n = 0; n < 4; ++n) {
        const float4 b4 = reinterpret_cast<const float4*>(bl)[n * 4 + q]; // feats 16n+4q+..
        v[n][0] = acc[n][0] + b4.x;
        v[n][1] = acc[n][1] + b4.y;
        v[n][2] = acc[n][2] + b4.z;
        v[n][3] = acc[n][3] + b4.w;
#pragma unroll
        for (int r = 0; r < 4; ++r) ss += v[n][r] * v[n][r];
    }
    ss += __shfl_xor(ss, 16, 64);
    ss += __shfl_xor(ss, 32, 64);
    const float nrm = 1.0f / fmaxf(sqrtf(ss), 1e-12f);

    if (!final_layer) {
        if (valid) {
            uint2* dst = reinterpret_cast<uint2*>(&h_out[(size_t)(base + c) * 64]);
#pragma unroll
            for (int n = 0; n < 4; ++n) {
                float o0 = fmaxf(v[n][0] * nrm, 0.f), o1 = fmaxf(v[n][1] * nrm, 0.f);
                float o2 = fmaxf(v[n][2] * nrm, 0.f), o3 = fmaxf(v[n][3] * nrm, 0.f);
                uint2 p;
                p.x = (unsigned int)f2bf(o0) | ((unsigned int)f2bf(o1) << 16);
                p.y = (unsigned int)f2bf(o2) | ((unsigned int)f2bf(o3) << 16);
                dst[n * 4 + q] = p;       // ushorts (base+c)*64 + 16n + 4q ..
            }
        }
    } else {
        float o[4][4];
#pragma unroll
        for (int n = 0; n < 4; ++n)
#pragma unroll
            for (int r = 0; r < 4; ++r)
                o[n][r] = valid ? fmaxf(v[n][r] * nrm, 0.f) : 0.f;

        const int lastn = min(base + 15, n_nodes - 1);
        const int gb0 = batch[base];
        if (gb0 == batch[lastn]) {
            // graph-uniform tile: reduce over the 16 nodes, 1 atomic per feat
#pragma unroll
            for (int n = 0; n < 4; ++n)
#pragma unroll
                for (int r = 0; r < 4; ++r) {
                    float s = o[n][r];
                    s += __shfl_xor(s, 1, 64);
                    s += __shfl_xor(s, 2, 64);
                    s += __shfl_xor(s, 4, 64);
                    s += __shfl_xor(s, 8, 64);
                    if (c == 0)
                        atomicAdd(&out[(size_t)gb0 * DFEAT + n * 16 + q * 4 + r], s);
                }
        } else {
            if (valid) {
                const int gb = batch[base + c];
#pragma unroll
                for (int n = 0; n < 4; ++n)
#pragma unroll
                    for (int r = 0; r < 4; ++r)
                        atomicAdd(&out[(size_t)gb * DFEAT + n * 16 + q * 4 + r], o[n][r]);
            }
        }
    }
}

// ============================================================================
extern "C" void kernel_launch(void* const* d_in, const int* in_sizes, int n_in,
                              void* d_out, int out_size, void* d_ws, size_t ws_size,
                              hipStream_t stream) {
    const float* x_raw = (const float*)d_in[0];
    const int*   eidx  = (const int*)d_in[1];
    const int*   batch = (const int*)d_in[2];
    const float* Wl0 = (const float*)d_in[3];
    const float* bl0 = (const float*)d_in[4];
    const float* Wr0 = (const float*)d_in[5];
    const float* Wl1 = (const float*)d_in[6];
    const float* bl1 = (const float*)d_in[7];
    const float* Wr1 = (const float*)d_in[8];
    const float* Wl2 = (const float*)d_in[9];
    const float* bl2 = (const float*)d_in[10];
    const float* Wr2 = (const float*)d_in[11];

    const int N = in_sizes[0] / DFEAT;
    const int E = in_sizes[1] / 2;
    const int* srcs = eidx;
    const int* dsts = eidx + E;
    float* out = (float*)d_out;

    const int NB = (N + 255) >> 8;   // buckets of 256 nodes; N=100000 -> 391 (<=512)

    char* ws = (char*)d_ws;
    auto align512 = [](size_t v) { return (v + 511) & ~(size_t)511; };
    size_t off = 0;
    int* rowptr = (int*)(ws + off); off += align512(((size_t)N + 1) * 4);
    int* col    = (int*)(ws + off); off += align512((size_t)E * 4);
    int* bhist  = (int*)(ws + off); off += align512(512 * 4);
    int* bbase  = (int*)(ws + off); off += align512(513 * 4);
    int* bcur   = (int*)(ws + off); off += align512(512 * 4);
    unsigned short* wfrag0 = (unsigned short*)(ws + off); off += align512(8192 * 2);
    unsigned short* wfrag1 = (unsigned short*)(ws + off); off += align512(8192 * 2);
    unsigned short* wfrag2 = (unsigned short*)(ws + off); off += align512(8192 * 2);
    unsigned short* xb = (unsigned short*)(ws + off); off += align512((size_t)N * DFEAT * 2);
    unsigned short* hA = (unsigned short*)(ws + off); off += align512((size_t)N * DFEAT * 2);
    unsigned short* hB = (unsigned short*)(ws + off);
    // pairbuf only lives during CSR build, which completes before hA is first
    // written (layer-0 fused kernel) -> alias it onto hA. E*4 (6.4MB) <= N*128B.
    unsigned int* pairbuf = (unsigned int*)hA;

    hipMemsetAsync(bhist, 0, 512 * 4, stream);
    hipMemsetAsync(out, 0, (size_t)out_size * 4, stream);

    // input fp32 -> bf16 (once) + weight fragments (once per layer)
    const int n4 = N * DFEAT / 4;
    cvt_bf16_kernel<<<(n4 + 255) / 256, 256, 0, stream>>>(x_raw, xb, n4);
    wfrag_cvt_kernel<<<4, 256, 0, stream>>>(Wl0, Wr0, wfrag0);
    wfrag_cvt_kernel<<<4, 256, 0, stream>>>(Wl1, Wr1, wfrag1);
    wfrag_cvt_kernel<<<4, 256, 0, stream>>>(Wl2, Wr2, wfrag2);

    // CSR build, binned two-pass (once)
    bucket_hist_kernel<<<512, 256, 0, stream>>>(dsts, bhist, E);
    bucket_scan_kernel<<<1, 256, 0, stream>>>(bhist, bbase, bcur);
    bin_kernel<<<(E + BIN_CH - 1) / BIN_CH, 256, 0, stream>>>(srcs, dsts, bcur, pairbuf, E);
    bucket_fill_kernel<<<NB, 256, 0, stream>>>(pairbuf, bbase, rowptr, col, N, E);

    // fused layers: 1 tile per block, 4 cooperative waves
    const int tiles = (N + 15) / 16;

    fused_sage_kernel<<<tiles, 256, 0, stream>>>(xb, rowptr, col, wfrag0, bl0,
                                                 hA, nullptr, nullptr, N, 0);
    fused_sage_kernel<<<tiles, 256, 0, stream>>>(hA, rowptr, col, wfrag1, bl1,
                                                 hB, nullptr, nullptr, N, 0);
    fused_sage_kernel<<<tiles, 256, 0, stream>>>(hB, rowptr, col, wfrag2, bl2,
                                                 nullptr, batch, out, N, 1);
}